// Round 2
// baseline (5972.269 us; speedup 1.0000x reference)
//
#include <hip/hip_runtime.h>
#include <cstddef>

#define BATCH  32768
#define T      11
#define INDIM  2
#define H      64
#define STEPS  80

__device__ __forceinline__ float sigmoidf_(float x) {
    float e = __expf(-x);
    return __fdividef(1.0f, 1.0f + e);
}

__device__ __forceinline__ float tanhf_(float x) {
    float e = __expf(-2.0f * x);
    return __fdividef(1.0f - e, 1.0f + e);
}

// One GRU cell for 64 rows (lane = row), gates split across 4 waves (16 j's each).
// hreg: this thread's register copy of the hidden state (pre-cell), used for matvec.
// hlds: transposed authoritative LDS copy hlds[k*64 + lane]; updated in place
//       (each (jj,lane) slot touched by exactly one thread -> no race).
template<int KIN>
__device__ __forceinline__ void gru_cell(
    const float* __restrict__ Wih, const float* __restrict__ Whh,
    const float* __restrict__ bih, const float* __restrict__ bhh,
    const float (&xin)[KIN], const float (&hreg)[64],
    float* __restrict__ hlds, int lane, int wv)
{
    // unroll 2: lets the scheduler prefetch the next u's s_load weight chunks
    // under the current u's FMA stream (2 waves/SIMD only partially hides it).
    #pragma unroll 2
    for (int u = 0; u < 16; ++u) {
        const int jj = wv * 16 + u;                 // wave-uniform
        float ar  = bih[jj]       + bhh[jj];
        float az  = bih[jj + 64]  + bhh[jj + 64];
        float ani = bih[jj + 128];
        float anh = bhh[jj + 128];
        const float* __restrict__ wi = Wih + jj * KIN;
        #pragma unroll
        for (int k = 0; k < KIN; ++k) {
            ar  += xin[k] * wi[k];
            az  += xin[k] * wi[64 * KIN + k];
            ani += xin[k] * wi[128 * KIN + k];
        }
        const float* __restrict__ wh = Whh + jj * 64;
        #pragma unroll
        for (int k = 0; k < 64; ++k) {
            ar  += hreg[k] * wh[k];
            az  += hreg[k] * wh[64 * 64 + k];
            anh += hreg[k] * wh[128 * 64 + k];
        }
        const float r = sigmoidf_(ar);
        const float z = sigmoidf_(az);
        const float n = tanhf_(ani + r * anh);
        const float hold = hlds[jj * 64 + lane];
        hlds[jj * 64 + lane] = (1.0f - z) * n + z * hold;
    }
}

// Copy the transposed LDS h state into a register array, and FORCE the loads
// to complete here (memory clobber) so the compiler cannot sink them into the
// matvec as per-FMA ds_read_b32 (that was round 1's 2.9x slowdown: VGPR=116
// proved h never lived in registers).
__device__ __forceinline__ void load_h(float (&hr)[64], const float* __restrict__ hlds, int lane) {
    #pragma unroll
    for (int k = 0; k < 64; ++k) hr[k] = hlds[k * 64 + lane];
    asm volatile("" ::: "memory");
}

__global__ __launch_bounds__(256, 2)
void gru_traj_kernel(
    const float* __restrict__ x,
    const float* __restrict__ eWih0, const float* __restrict__ eWhh0,
    const float* __restrict__ ebih0, const float* __restrict__ ebhh0,
    const float* __restrict__ eWih1, const float* __restrict__ eWhh1,
    const float* __restrict__ ebih1, const float* __restrict__ ebhh1,
    const float* __restrict__ dWih0, const float* __restrict__ dWhh0,
    const float* __restrict__ dbih0, const float* __restrict__ dbhh0,
    const float* __restrict__ dWih1, const float* __restrict__ dWhh1,
    const float* __restrict__ dbih1, const float* __restrict__ dbhh1,
    const float* __restrict__ fcW,  const float* __restrict__ fcb,
    float* __restrict__ out)
{
    __shared__ float h0s[64 * 64];   // [k][lane] transposed; lane%32 banks -> 2-way alias (free)
    __shared__ float h1s[64 * 64];

    const int tid  = threadIdx.x;
    const int lane = tid & 63;
    const int wv   = __builtin_amdgcn_readfirstlane(tid >> 6);
    const int row  = blockIdx.x * 64 + lane;

    for (int i = tid; i < 64 * 64; i += 256) { h0s[i] = 0.0f; h1s[i] = 0.0f; }

    float h0r[64], h1r[64];
    #pragma unroll
    for (int k = 0; k < 64; ++k) { h0r[k] = 0.0f; h1r[k] = 0.0f; }
    __syncthreads();

    const float* __restrict__ xrow = x + (size_t)row * (T * INDIM);
    float xin[2];

    // ---------------- encoder ----------------
    for (int t = 0; t < T; ++t) {
        float2 xv = *(const float2*)(xrow + t * INDIM);
        xin[0] = xv.x; xin[1] = xv.y;

        gru_cell<2>(eWih0, eWhh0, ebih0, ebhh0, xin, h0r, h0s, lane, wv);
        __syncthreads();
        load_h(h0r, h0s, lane);
        __syncthreads();

        gru_cell<64>(eWih1, eWhh1, ebih1, ebhh1, h0r, h1r, h1s, lane, wv);
        __syncthreads();
        load_h(h1r, h1s, lane);
        __syncthreads();
    }

    // ---------------- decoder ----------------
    {
        float2 xl = *(const float2*)(xrow + (T - 1) * INDIM);
        xin[0] = xl.x; xin[1] = xl.y;
    }
    float* __restrict__ outrow = out + (size_t)row * (STEPS * INDIM);

    for (int s = 0; s < STEPS; ++s) {
        gru_cell<2>(dWih0, dWhh0, dbih0, dbhh0, xin, h0r, h0s, lane, wv);
        __syncthreads();
        load_h(h0r, h0s, lane);
        __syncthreads();

        gru_cell<64>(dWih1, dWhh1, dbih1, dbhh1, h0r, h1r, h1s, lane, wv);
        __syncthreads();
        load_h(h1r, h1s, lane);
        __syncthreads();

        float p0 = fcb[0], p1 = fcb[1];
        #pragma unroll
        for (int k = 0; k < 64; ++k) {
            p0 += h1r[k] * fcW[k];
            p1 += h1r[k] * fcW[64 + k];
        }
        xin[0] = p0; xin[1] = p1;
        if (wv == 0) {
            *(float2*)(outrow + s * INDIM) = make_float2(p0, p1);
        }
    }
}

extern "C" void kernel_launch(void* const* d_in, const int* in_sizes, int n_in,
                              void* d_out, int out_size, void* d_ws, size_t ws_size,
                              hipStream_t stream) {
    (void)n_in; (void)out_size; (void)d_ws; (void)ws_size;

    const float* x     = (const float*)d_in[0];
    const float* eWih0 = (const float*)d_in[1];
    const float* eWhh0 = (const float*)d_in[2];
    const float* ebih0 = (const float*)d_in[3];
    const float* ebhh0 = (const float*)d_in[4];
    const float* eWih1 = (const float*)d_in[5];
    const float* eWhh1 = (const float*)d_in[6];
    const float* ebih1 = (const float*)d_in[7];
    const float* ebhh1 = (const float*)d_in[8];
    const float* dWih0 = (const float*)d_in[9];
    const float* dWhh0 = (const float*)d_in[10];
    const float* dbih0 = (const float*)d_in[11];
    const float* dbhh0 = (const float*)d_in[12];
    const float* dWih1 = (const float*)d_in[13];
    const float* dWhh1 = (const float*)d_in[14];
    const float* dbih1 = (const float*)d_in[15];
    const float* dbhh1 = (const float*)d_in[16];
    const float* fcW   = (const float*)d_in[17];
    const float* fcb   = (const float*)d_in[18];
    float* out = (float*)d_out;

    const int b = in_sizes[0] / (T * INDIM);   // 32768
    dim3 grid(b / 64), block(256);
    hipLaunchKernelGGL(gru_traj_kernel, grid, block, 0, stream,
        x, eWih0, eWhh0, ebih0, ebhh0, eWih1, eWhh1, ebih1, ebhh1,
        dWih0, dWhh0, dbih0, dbhh0, dWih1, dWhh1, dbih1, dbhh1,
        fcW, fcb, out);
}

// Round 3
// 832.637 us; speedup vs baseline: 7.1727x; 7.1727x over previous
//
#include <hip/hip_runtime.h>
#include <cstddef>

#define T_SEQ  11
#define STEPS  80
#define HS     72   // padded LDS row stride in halves (64 + 8: 2-way bank alias = free)

typedef _Float16 f16;
typedef _Float16 f16x8 __attribute__((ext_vector_type(8)));
typedef float    f32x4 __attribute__((ext_vector_type(4)));

__device__ __forceinline__ f32x4 mfma16(f16x8 a, f16x8 b, f32x4 c) {
    return __builtin_amdgcn_mfma_f32_16x16x32_f16(a, b, c, 0, 0, 0);
}

__device__ __forceinline__ float sigf(float x) {
    return __fdividef(1.0f, 1.0f + __expf(-x));
}
__device__ __forceinline__ float tanhf_(float x) {
    float e = __expf(2.0f * x);
    return 1.0f - __fdividef(2.0f, e + 1.0f);
}

// B-fragment (B^T layout == A layout): lane holds W[row][k0..k0+7] cast to f16.
__device__ __forceinline__ f16x8 load_wfrag(const float* __restrict__ W, int K, int row, int k0) {
    const float* p = W + row * K + k0;
    f16x8 r;
    #pragma unroll
    for (int i = 0; i < 8; ++i) r[i] = (f16)p[i];
    return r;
}

struct Frags {
    f16x8 h0R[2], h0Z[2], h0N[2];   // layer0 Whh
    f16x8 i1R[2], i1Z[2], i1N[2];   // layer1 Wih
    f16x8 h1R[2], h1Z[2], h1N[2];   // layer1 Whh
    float w0r, w1r, w0z, w1z, w0n, w1n;   // layer0 Wih (K=2), this lane's j
    float bir, biz, bin;                  // bih0 (gi side)
    float bhr, bhz, bhn;                  // bhh0 (gh side, folded into acc init)
    float b1r, b1z, b1in, b1hn;           // layer1 biases
};

__device__ __forceinline__ void load_frags(Frags& F, int jcol, int quad,
    const float* __restrict__ Wih0, const float* __restrict__ Whh0,
    const float* __restrict__ bih0, const float* __restrict__ bhh0,
    const float* __restrict__ Wih1, const float* __restrict__ Whh1,
    const float* __restrict__ bih1, const float* __restrict__ bhh1)
{
    #pragma unroll
    for (int ks = 0; ks < 2; ++ks) {
        const int k0 = ks * 32 + quad * 8;
        F.h0R[ks] = load_wfrag(Whh0, 64, jcol,       k0);
        F.h0Z[ks] = load_wfrag(Whh0, 64, jcol + 64,  k0);
        F.h0N[ks] = load_wfrag(Whh0, 64, jcol + 128, k0);
        F.i1R[ks] = load_wfrag(Wih1, 64, jcol,       k0);
        F.i1Z[ks] = load_wfrag(Wih1, 64, jcol + 64,  k0);
        F.i1N[ks] = load_wfrag(Wih1, 64, jcol + 128, k0);
        F.h1R[ks] = load_wfrag(Whh1, 64, jcol,       k0);
        F.h1Z[ks] = load_wfrag(Whh1, 64, jcol + 64,  k0);
        F.h1N[ks] = load_wfrag(Whh1, 64, jcol + 128, k0);
    }
    F.w0r = Wih0[jcol * 2];           F.w1r = Wih0[jcol * 2 + 1];
    F.w0z = Wih0[(jcol + 64) * 2];    F.w1z = Wih0[(jcol + 64) * 2 + 1];
    F.w0n = Wih0[(jcol + 128) * 2];   F.w1n = Wih0[(jcol + 128) * 2 + 1];
    F.bir = bih0[jcol]; F.biz = bih0[jcol + 64]; F.bin = bih0[jcol + 128];
    F.bhr = bhh0[jcol]; F.bhz = bhh0[jcol + 64]; F.bhn = bhh0[jcol + 128];
    F.b1r  = bih1[jcol] + bhh1[jcol];
    F.b1z  = bih1[jcol + 64] + bhh1[jcol + 64];
    F.b1in = bih1[jcol + 128];
    F.b1hn = bhh1[jcol + 128];
}

// Layer-0 cell: gates_h = h0 @ Whh0^T (MFMA); gi from x (K=2, VALU).
__device__ __forceinline__ void cell_l0(const Frags& F, f16* h0s,
    const float* xb, int xstride, float (&hreg)[16], int col, int quad, int jcol)
{
    f32x4 aR[4], aZ[4], aN[4];
    #pragma unroll
    for (int mt = 0; mt < 4; ++mt) {
        aR[mt] = (f32x4){F.bhr, F.bhr, F.bhr, F.bhr};
        aZ[mt] = (f32x4){F.bhz, F.bhz, F.bhz, F.bhz};
        aN[mt] = (f32x4){F.bhn, F.bhn, F.bhn, F.bhn};
    }
    #pragma unroll
    for (int ks = 0; ks < 2; ++ks) {
        #pragma unroll
        for (int mt = 0; mt < 4; ++mt) {
            f16x8 a = *(const f16x8*)&h0s[(mt * 16 + col) * HS + ks * 32 + quad * 8];
            aR[mt] = mfma16(a, F.h0R[ks], aR[mt]);
            aZ[mt] = mfma16(a, F.h0Z[ks], aZ[mt]);
            aN[mt] = mfma16(a, F.h0N[ks], aN[mt]);
        }
    }
    __syncthreads();   // all waves' A-reads of h0s done before in-place update
    #pragma unroll
    for (int mt = 0; mt < 4; ++mt) {
        #pragma unroll
        for (int rg = 0; rg < 4; ++rg) {
            const int row = mt * 16 + quad * 4 + rg;
            const float x0 = xb[row * xstride], x1 = xb[row * xstride + 1];
            const float gir = fmaf(x1, F.w1r, fmaf(x0, F.w0r, F.bir));
            const float giz = fmaf(x1, F.w1z, fmaf(x0, F.w0z, F.biz));
            const float gin = fmaf(x1, F.w1n, fmaf(x0, F.w0n, F.bin));
            const float r = sigf(gir + aR[mt][rg]);
            const float z = sigf(giz + aZ[mt][rg]);
            const float n = tanhf_(gin + r * aN[mt][rg]);
            const float ho = hreg[mt * 4 + rg];
            const float hn = fmaf(z, ho - n, n);
            hreg[mt * 4 + rg] = hn;
            h0s[row * HS + jcol] = (f16)hn;
        }
    }
    __syncthreads();
}

// Layer-1 cell: gi = h0_new @ Wih1^T, gh = h1 @ Whh1^T (both MFMA).
__device__ __forceinline__ void cell_l1(const Frags& F, const f16* h0s, f16* h1s,
    float (&hreg)[16], int col, int quad, int jcol)
{
    f32x4 aR[4], aZ[4], aNi[4], aNh[4];
    #pragma unroll
    for (int mt = 0; mt < 4; ++mt) {
        aR[mt]  = (f32x4){F.b1r, F.b1r, F.b1r, F.b1r};
        aZ[mt]  = (f32x4){F.b1z, F.b1z, F.b1z, F.b1z};
        aNi[mt] = (f32x4){F.b1in, F.b1in, F.b1in, F.b1in};
        aNh[mt] = (f32x4){F.b1hn, F.b1hn, F.b1hn, F.b1hn};
    }
    #pragma unroll
    for (int ks = 0; ks < 2; ++ks) {
        #pragma unroll
        for (int mt = 0; mt < 4; ++mt) {
            f16x8 a0 = *(const f16x8*)&h0s[(mt * 16 + col) * HS + ks * 32 + quad * 8];
            aR[mt]  = mfma16(a0, F.i1R[ks], aR[mt]);
            aZ[mt]  = mfma16(a0, F.i1Z[ks], aZ[mt]);
            aNi[mt] = mfma16(a0, F.i1N[ks], aNi[mt]);
            f16x8 a1 = *(const f16x8*)&h1s[(mt * 16 + col) * HS + ks * 32 + quad * 8];
            aR[mt]  = mfma16(a1, F.h1R[ks], aR[mt]);
            aZ[mt]  = mfma16(a1, F.h1Z[ks], aZ[mt]);
            aNh[mt] = mfma16(a1, F.h1N[ks], aNh[mt]);
        }
    }
    __syncthreads();
    #pragma unroll
    for (int mt = 0; mt < 4; ++mt) {
        #pragma unroll
        for (int rg = 0; rg < 4; ++rg) {
            const int row = mt * 16 + quad * 4 + rg;
            const float r = sigf(aR[mt][rg]);
            const float z = sigf(aZ[mt][rg]);
            const float n = tanhf_(aNi[mt][rg] + r * aNh[mt][rg]);
            const float ho = hreg[mt * 4 + rg];
            const float hn = fmaf(z, ho - n, n);
            hreg[mt * 4 + rg] = hn;
            h1s[row * HS + jcol] = (f16)hn;
        }
    }
    __syncthreads();
}

__global__ __launch_bounds__(256, 2)
void gru_traj_mfma(
    const float* __restrict__ x,
    const float* __restrict__ eWih0, const float* __restrict__ eWhh0,
    const float* __restrict__ ebih0, const float* __restrict__ ebhh0,
    const float* __restrict__ eWih1, const float* __restrict__ eWhh1,
    const float* __restrict__ ebih1, const float* __restrict__ ebhh1,
    const float* __restrict__ dWih0, const float* __restrict__ dWhh0,
    const float* __restrict__ dbih0, const float* __restrict__ dbhh0,
    const float* __restrict__ dWih1, const float* __restrict__ dWhh1,
    const float* __restrict__ dbih1, const float* __restrict__ dbhh1,
    const float* __restrict__ fcW,  const float* __restrict__ fcb,
    float* __restrict__ out)
{
    __shared__ f16   h0s[64 * HS];
    __shared__ f16   h1s[64 * HS];
    __shared__ float xenc[64 * (T_SEQ * 2)];   // [row][t*2+c], direct global copy
    __shared__ float xdec[64 * 2];

    const int tid  = threadIdx.x;
    const int lane = tid & 63;
    const int w    = __builtin_amdgcn_readfirstlane(tid >> 6);
    const int quad = lane >> 4;
    const int col  = lane & 15;
    const int jcol = w * 16 + col;      // this lane's gate index j in [0,64)
    const int r0   = blockIdx.x * 64;

    for (int i = tid; i < 64 * HS; i += 256) { h0s[i] = (f16)0.f; h1s[i] = (f16)0.f; }
    for (int i = tid; i < 64 * (T_SEQ * 2); i += 256) xenc[i] = x[(size_t)r0 * (T_SEQ * 2) + i];

    float hreg0[16], hreg1[16];
    #pragma unroll
    for (int i = 0; i < 16; ++i) { hreg0[i] = 0.f; hreg1[i] = 0.f; }

    Frags F;
    load_frags(F, jcol, quad, eWih0, eWhh0, ebih0, ebhh0, eWih1, eWhh1, ebih1, ebhh1);
    __syncthreads();

    // ---------------- encoder ----------------
    #pragma unroll 1
    for (int t = 0; t < T_SEQ; ++t) {
        cell_l0(F, h0s, &xenc[t * 2], T_SEQ * 2, hreg0, col, quad, jcol);
        cell_l1(F, h0s, h1s, hreg1, col, quad, jcol);
    }

    // ---------------- phase switch ----------------
    load_frags(F, jcol, quad, dWih0, dWhh0, dbih0, dbhh0, dWih1, dWhh1, dbih1, dbhh1);
    f16x8 fcf[2];
    {
        const int rw = (col < 2) ? col : 0;   // pad N to 16; garbage cols ignored
        fcf[0] = load_wfrag(fcW, 64, rw, quad * 8);
        fcf[1] = load_wfrag(fcW, 64, rw, 32 + quad * 8);
    }
    const float pb = (col < 2) ? fcb[col] : 0.f;
    if (tid < 128) xdec[tid] = xenc[(tid >> 1) * (T_SEQ * 2) + (T_SEQ - 1) * 2 + (tid & 1)];
    __syncthreads();

    float* __restrict__ outp = out + (size_t)r0 * (STEPS * 2);

    // ---------------- decoder ----------------
    #pragma unroll 1
    for (int s = 0; s < STEPS; ++s) {
        cell_l0(F, h0s, xdec, 2, hreg0, col, quad, jcol);
        cell_l1(F, h0s, h1s, hreg1, col, quad, jcol);

        // FC head: wave w handles M-tile w (rows 16w..16w+15), N padded to 16.
        f32x4 p = (f32x4){pb, pb, pb, pb};
        #pragma unroll
        for (int ks = 0; ks < 2; ++ks) {
            f16x8 a = *(const f16x8*)&h1s[(w * 16 + col) * HS + ks * 32 + quad * 8];
            p = mfma16(a, fcf[ks], p);
        }
        if (col < 2) {
            #pragma unroll
            for (int rg = 0; rg < 4; ++rg) {
                const int row = w * 16 + quad * 4 + rg;
                const float v = p[rg];
                outp[(size_t)row * (STEPS * 2) + s * 2 + col] = v;
                xdec[row * 2 + col] = v;
            }
        }
        __syncthreads();
    }
}

extern "C" void kernel_launch(void* const* d_in, const int* in_sizes, int n_in,
                              void* d_out, int out_size, void* d_ws, size_t ws_size,
                              hipStream_t stream) {
    (void)n_in; (void)out_size; (void)d_ws; (void)ws_size;

    const float* x     = (const float*)d_in[0];
    const float* eWih0 = (const float*)d_in[1];
    const float* eWhh0 = (const float*)d_in[2];
    const float* ebih0 = (const float*)d_in[3];
    const float* ebhh0 = (const float*)d_in[4];
    const float* eWih1 = (const float*)d_in[5];
    const float* eWhh1 = (const float*)d_in[6];
    const float* ebih1 = (const float*)d_in[7];
    const float* ebhh1 = (const float*)d_in[8];
    const float* dWih0 = (const float*)d_in[9];
    const float* dWhh0 = (const float*)d_in[10];
    const float* dbih0 = (const float*)d_in[11];
    const float* dbhh0 = (const float*)d_in[12];
    const float* dWih1 = (const float*)d_in[13];
    const float* dWhh1 = (const float*)d_in[14];
    const float* dbih1 = (const float*)d_in[15];
    const float* dbhh1 = (const float*)d_in[16];
    const float* fcW   = (const float*)d_in[17];
    const float* fcb   = (const float*)d_in[18];
    float* out = (float*)d_out;

    const int b = in_sizes[0] / (T_SEQ * 2);   // 32768
    dim3 grid(b / 64), block(256);
    hipLaunchKernelGGL(gru_traj_mfma, grid, block, 0, stream,
        x, eWih0, eWhh0, ebih0, ebhh0, eWih1, eWhh1, ebih1, ebhh1,
        dWih0, dWhh0, dbih0, dbhh0, dWih1, dWhh1, dbih1, dbhh1,
        fcW, fcb, out);
}

// Round 5
// 765.554 us; speedup vs baseline: 7.8012x; 1.0876x over previous
//
#include <hip/hip_runtime.h>
#include <cstddef>

#define T_SEQ 11
#define STEPS 80

typedef _Float16 f16;
typedef _Float16 f16x4 __attribute__((ext_vector_type(4)));
typedef _Float16 f16x8 __attribute__((ext_vector_type(8)));
typedef float    f32x4 __attribute__((ext_vector_type(4)));

__device__ __forceinline__ f32x4 mfma16(f16x8 a, f16x8 b, f32x4 c) {
    return __builtin_amdgcn_mfma_f32_16x16x32_f16(a, b, c, 0, 0, 0);
}
__device__ __forceinline__ float sig1(float x) {
    return __fdividef(1.f, 1.f + __expf(-x));
}
__device__ __forceinline__ float th1(float x) {
    return 1.f - __fdividef(2.f, __expf(2.f * x) + 1.f);
}

// A-frag: lane holds W[row][k0..k0+7] (m = lane&15 selects row within tile).
__device__ __forceinline__ f16x8 wfrag(const float* __restrict__ W, int row, int k0) {
    f16x8 r;
    #pragma unroll
    for (int i = 0; i < 8; ++i) r[i] = (f16)W[row * 64 + k0 + i];
    return r;
}
// Composed decoder-l0 gi weights: Wcomb[g][k] = Wih0[g][0]*fcW[0][k] + Wih0[g][1]*fcW[1][k]
__device__ __forceinline__ f16x8 cfrag(const float* __restrict__ Wih0,
                                       const float* __restrict__ fcW, int row, int k0) {
    f16x8 r;
    #pragma unroll
    for (int i = 0; i < 8; ++i)
        r[i] = (f16)(Wih0[row * 2] * fcW[k0 + i] + Wih0[row * 2 + 1] * fcW[64 + k0 + i]);
    return r;
}

struct WSet {
    f16x8 xR[2], xZ[2], xN[2];   // gi-source weights (MFMA path)
    f16x8 hR[2], hZ[2], hN[2];   // recurrent weights
    f32x4 bR, bZ, bNi, bNh;      // biases, vector over rg (j = j4+rg)
};

__device__ __forceinline__ void load_h_side(WSet& W,
    const float* __restrict__ Whh, const float* __restrict__ bih,
    const float* __restrict__ bhh, int jA, int j4, int quad)
{
    #pragma unroll
    for (int ks = 0; ks < 2; ++ks) {
        const int k0 = ks * 32 + quad * 8;
        W.hR[ks] = wfrag(Whh, jA,       k0);
        W.hZ[ks] = wfrag(Whh, jA + 64,  k0);
        W.hN[ks] = wfrag(Whh, jA + 128, k0);
    }
    #pragma unroll
    for (int rg = 0; rg < 4; ++rg) {
        W.bR[rg]  = bih[j4 + rg] + bhh[j4 + rg];
        W.bZ[rg]  = bih[64 + j4 + rg] + bhh[64 + j4 + rg];
        W.bNi[rg] = bih[128 + j4 + rg];
        W.bNh[rg] = bhh[128 + j4 + rg];
    }
}
__device__ __forceinline__ void load_x_side(WSet& W, const float* __restrict__ Wx,
                                            int jA, int quad)
{
    #pragma unroll
    for (int ks = 0; ks < 2; ++ks) {
        const int k0 = ks * 32 + quad * 8;
        W.xR[ks] = wfrag(Wx, jA,       k0);
        W.xZ[ks] = wfrag(Wx, jA + 64,  k0);
        W.xN[ks] = wfrag(Wx, jA + 128, k0);
    }
}

// One GRU cell, D[j][row] orientation. Reads B-frags (h) from swizzled LDS,
// writes new h (f16x4 per row-tile) to Dst. hreg keeps the fp32 h master copy.
template<bool XM>
__device__ __forceinline__ void cell(const WSet& W,
    const f16* __restrict__ Xs, const f16* __restrict__ Hs, f16* __restrict__ Dst,
    float (&hreg)[16], const f32x4* __restrict__ xw, const float2* __restrict__ xv,
    int ro0, int ro1, int wo)
{
    #pragma unroll
    for (int mt = 0; mt < 4; ++mt) {
        f32x4 aR = W.bR, aZ = W.bZ, aNi = W.bNi, aNh = W.bNh;
        const int mo = mt * 1024;
        f16x8 hb0 = *(const f16x8*)(Hs + ro0 + mo);
        f16x8 hb1 = *(const f16x8*)(Hs + ro1 + mo);
        aR  = mfma16(W.hR[0], hb0, aR);  aR  = mfma16(W.hR[1], hb1, aR);
        aZ  = mfma16(W.hZ[0], hb0, aZ);  aZ  = mfma16(W.hZ[1], hb1, aZ);
        aNh = mfma16(W.hN[0], hb0, aNh); aNh = mfma16(W.hN[1], hb1, aNh);
        if constexpr (XM) {
            f16x8 xb0 = *(const f16x8*)(Xs + ro0 + mo);
            f16x8 xb1 = *(const f16x8*)(Xs + ro1 + mo);
            aR  = mfma16(W.xR[0], xb0, aR);  aR  = mfma16(W.xR[1], xb1, aR);
            aZ  = mfma16(W.xZ[0], xb0, aZ);  aZ  = mfma16(W.xZ[1], xb1, aZ);
            aNi = mfma16(W.xN[0], xb0, aNi); aNi = mfma16(W.xN[1], xb1, aNi);
        } else {
            const float x0 = xv[mt].x, x1 = xv[mt].y;
            aR  += x0 * xw[0] + x1 * xw[1];
            aZ  += x0 * xw[2] + x1 * xw[3];
            aNi += x0 * xw[4] + x1 * xw[5];
        }
        f16x4 o;
        #pragma unroll
        for (int i = 0; i < 4; ++i) {
            const float r = sig1(aR[i]);
            const float z = sig1(aZ[i]);
            const float n = th1(aNi[i] + r * aNh[i]);
            const float ho = hreg[mt * 4 + i];
            const float hn = n + z * (ho - n);
            hreg[mt * 4 + i] = hn;
            o[i] = (f16)hn;
        }
        *(f16x4*)(Dst + wo + mo) = o;   // one ds_write_b64, swizzle-aligned
    }
}

__global__ __launch_bounds__(256, 2)
void gru_traj_mfma2(
    const float* __restrict__ x,
    const float* __restrict__ eWih0, const float* __restrict__ eWhh0,
    const float* __restrict__ ebih0, const float* __restrict__ ebhh0,
    const float* __restrict__ eWih1, const float* __restrict__ eWhh1,
    const float* __restrict__ ebih1, const float* __restrict__ ebhh1,
    const float* __restrict__ dWih0, const float* __restrict__ dWhh0,
    const float* __restrict__ dbih0, const float* __restrict__ dbhh0,
    const float* __restrict__ dWih1, const float* __restrict__ dWhh1,
    const float* __restrict__ dbih1, const float* __restrict__ dbhh1,
    const float* __restrict__ fcW,  const float* __restrict__ fcb,
    float* __restrict__ out)
{
    // 4 h buffers (double-buffered per layer), XOR-swizzled, no padding.
    __shared__ f16 hbuf[4][64 * 64];     // [0,1]=h0, [2,3]=h1
    __shared__ float2 xe[64 * T_SEQ];

    const int tid  = threadIdx.x;
    const int lane = tid & 63;
    const int w    = __builtin_amdgcn_readfirstlane(tid >> 6);
    const int quad = lane >> 4;
    const int col  = lane & 15;
    const int r0   = blockIdx.x * 64;

    for (int i = tid; i < 64 * T_SEQ; i += 256)
        xe[i] = ((const float2*)x)[(size_t)r0 * T_SEQ + i];
    for (int i = tid; i < 64 * 64; i += 256) { hbuf[0][i] = (f16)0.f; hbuf[2][i] = (f16)0.f; }

    // Swizzled offsets (halves): phys(row,k) = row*64 + (((k>>3)^(row&7))<<3) + (k&7)
    const int c7  = col & 7;
    const int ro0 = col * 64 + ((quad ^ c7) << 3);             // B-frag read, ks=0
    const int ro1 = col * 64 + (((4 + quad) ^ c7) << 3);       // B-frag read, ks=1
    const int wo  = col * 64 + ((((w << 1) | (quad >> 1)) ^ c7) << 3) + ((quad & 1) << 2);

    const int jA = w * 16 + col;        // A-frag W-row base (m = col)
    const int j4 = w * 16 + quad * 4;   // epilogue/bias j base (m = quad*4+rg)

    float hreg0[16], hreg1[16];
    #pragma unroll
    for (int i = 0; i < 16; ++i) { hreg0[i] = 0.f; hreg1[i] = 0.f; }

    WSet W0, W1;
    load_h_side(W0, eWhh0, ebih0, ebhh0, jA, j4, quad);
    load_h_side(W1, eWhh1, ebih1, ebhh1, jA, j4, quad);
    load_x_side(W1, eWih1, jA, quad);
    f32x4 xw[6];
    #pragma unroll
    for (int rg = 0; rg < 4; ++rg) {
        xw[0][rg] = eWih0[(j4 + rg) * 2];        xw[1][rg] = eWih0[(j4 + rg) * 2 + 1];
        xw[2][rg] = eWih0[(64 + j4 + rg) * 2];   xw[3][rg] = eWih0[(64 + j4 + rg) * 2 + 1];
        xw[4][rg] = eWih0[(128 + j4 + rg) * 2];  xw[5][rg] = eWih0[(128 + j4 + rg) * 2 + 1];
    }
    int c0 = 0, c1 = 0;
    __syncthreads();

    // ---------------- encoder: 1 barrier per pair ----------------
    #pragma unroll 1
    for (int t = 0; t < T_SEQ; ++t) {
        float2 xv[4];
        #pragma unroll
        for (int mt = 0; mt < 4; ++mt) xv[mt] = xe[(mt * 16 + col) * T_SEQ + t];
        cell<false>(W0, hbuf[c0], hbuf[c0], hbuf[c0 ^ 1], hreg0, xw, xv, ro0, ro1, wo);
        c0 ^= 1; __syncthreads();
        cell<true>(W1, hbuf[c0], hbuf[2 + c1], hbuf[2 + (c1 ^ 1)], hreg1, nullptr, nullptr, ro0, ro1, wo);
        c1 ^= 1;
    }

    // ---------------- phase switch ----------------
    load_h_side(W0, dWhh0, dbih0, dbhh0, jA, j4, quad);
    #pragma unroll
    for (int ks = 0; ks < 2; ++ks) {
        const int k0 = ks * 32 + quad * 8;
        W0.xR[ks] = cfrag(dWih0, fcW, jA,       k0);
        W0.xZ[ks] = cfrag(dWih0, fcW, jA + 64,  k0);
        W0.xN[ks] = cfrag(dWih0, fcW, jA + 128, k0);
    }
    #pragma unroll
    for (int rg = 0; rg < 4; ++rg) {   // fold fc_b through Wih0 into gi biases
        const int j = j4 + rg;
        W0.bR[rg]  += dWih0[j * 2] * fcb[0]         + dWih0[j * 2 + 1] * fcb[1];
        W0.bZ[rg]  += dWih0[(64 + j) * 2] * fcb[0]  + dWih0[(64 + j) * 2 + 1] * fcb[1];
        W0.bNi[rg] += dWih0[(128 + j) * 2] * fcb[0] + dWih0[(128 + j) * 2 + 1] * fcb[1];
    }
    load_h_side(W1, dWhh1, dbih1, dbhh1, jA, j4, quad);
    load_x_side(W1, dWih1, jA, quad);
    #pragma unroll
    for (int rg = 0; rg < 4; ++rg) {   // x-path weights for decoder step 0
        xw[0][rg] = dWih0[(j4 + rg) * 2];        xw[1][rg] = dWih0[(j4 + rg) * 2 + 1];
        xw[2][rg] = dWih0[(64 + j4 + rg) * 2];   xw[3][rg] = dWih0[(64 + j4 + rg) * 2 + 1];
        xw[4][rg] = dWih0[(128 + j4 + rg) * 2];  xw[5][rg] = dWih0[(128 + j4 + rg) * 2 + 1];
    }
    f16x8 fcf[2];
    #pragma unroll
    for (int ks = 0; ks < 2; ++ks) {
        #pragma unroll
        for (int i = 0; i < 8; ++i) fcf[ks][i] = (f16)0.f;
        if (col < 2) fcf[ks] = wfrag(fcW, col, ks * 32 + quad * 8);
    }
    f32x4 pb;
    #pragma unroll
    for (int rg = 0; rg < 4; ++rg) pb[rg] = (quad == 0 && rg < 2) ? fcb[rg] : 0.f;
    float2 xv0[4];
    #pragma unroll
    for (int mt = 0; mt < 4; ++mt) xv0[mt] = xe[(mt * 16 + col) * T_SEQ + (T_SEQ - 1)];

    float* __restrict__ outp = out + (size_t)r0 * (STEPS * 2);

    // ---------------- decoder: 2 barriers per step ----------------
    #pragma unroll 1
    for (int s = 0; s < STEPS; ++s) {
        if (s == 0)
            cell<false>(W0, hbuf[c0], hbuf[c0], hbuf[c0 ^ 1], hreg0, xw, xv0, ro0, ro1, wo);
        else
            cell<true>(W0, hbuf[2 + c1], hbuf[c0], hbuf[c0 ^ 1], hreg0, nullptr, nullptr, ro0, ro1, wo);
        c0 ^= 1; __syncthreads();
        cell<true>(W1, hbuf[c0], hbuf[2 + c1], hbuf[2 + (c1 ^ 1)], hreg1, nullptr, nullptr, ro0, ro1, wo);
        c1 ^= 1; __syncthreads();

        // FC head on the fresh h1 (wave w covers rows 16w..16w+15)
        f16x8 hb0 = *(const f16x8*)(hbuf[2 + c1] + ro0 + w * 1024);
        f16x8 hb1 = *(const f16x8*)(hbuf[2 + c1] + ro1 + w * 1024);
        f32x4 p = pb;
        p = mfma16(fcf[0], hb0, p);
        p = mfma16(fcf[1], hb1, p);
        if (quad == 0) {
            *(float2*)&outp[(size_t)(w * 16 + col) * (STEPS * 2) + s * 2] =
                make_float2(p[0], p[1]);
        }
    }
}

extern "C" void kernel_launch(void* const* d_in, const int* in_sizes, int n_in,
                              void* d_out, int out_size, void* d_ws, size_t ws_size,
                              hipStream_t stream) {
    (void)n_in; (void)out_size; (void)d_ws; (void)ws_size;

    const float* x     = (const float*)d_in[0];
    const float* eWih0 = (const float*)d_in[1];
    const float* eWhh0 = (const float*)d_in[2];
    const float* ebih0 = (const float*)d_in[3];
    const float* ebhh0 = (const float*)d_in[4];
    const float* eWih1 = (const float*)d_in[5];
    const float* eWhh1 = (const float*)d_in[6];
    const float* ebih1 = (const float*)d_in[7];
    const float* ebhh1 = (const float*)d_in[8];
    const float* dWih0 = (const float*)d_in[9];
    const float* dWhh0 = (const float*)d_in[10];
    const float* dbih0 = (const float*)d_in[11];
    const float* dbhh0 = (const float*)d_in[12];
    const float* dWih1 = (const float*)d_in[13];
    const float* dWhh1 = (const float*)d_in[14];
    const float* dbih1 = (const float*)d_in[15];
    const float* dbhh1 = (const float*)d_in[16];
    const float* fcW   = (const float*)d_in[17];
    const float* fcb   = (const float*)d_in[18];
    float* out = (float*)d_out;

    const int b = in_sizes[0] / (T_SEQ * 2);   // 32768
    dim3 grid(b / 64), block(256);
    hipLaunchKernelGGL(gru_traj_mfma2, grid, block, 0, stream,
        x, eWih0, eWhh0, ebih0, ebhh0, eWih1, eWhh1, ebih1, ebhh1,
        dWih0, dWhh0, dbih0, dbhh0, dWih1, dWhh1, dbih1, dbhh1,
        fcW, fcb, out);
}